// Round 5
// baseline (31.815 us; speedup 1.0000x reference)
//
#include <hip/hip_runtime.h>

// out[z, k] = sum_{n in segment(k)} vals[n] * x1[z, i_idx[n]] * x2[z, j_idx[n]]
//
// Structure facts (from the reference generator _build_sparse_tp):
//  * entries are ordered so that every output row k is ONE contiguous run in n
//    -- BUT runs are in generator path order, NOT ascending k (dst relabels
//       values only). So bounds must be stored per-k (seg_start/seg_end),
//       NOT as a row_ptr CSR. (R4's row_ptr assumption was the bug.)
//  * every k in [0, dim_out) appears => boundary detection fully populates
//    both arrays, no memset needed (verified: R3 passed without memset).
//
// R5: ZPT=32 (amortize per-k latency chains), software-pipelined entry loop,
// LDS transposed [i][t] with STRIDE=36 dwords (16B-aligned ds_read_b128,
// 8 quad-bank groups covered), packed (i|j<<16, val) int2 entries.

#define ZPT 32
#define BLK 512
#define DIM_IN 144
#define STRIDE 36

__global__ void prep_kernel(const int* __restrict__ k_idx,
                            const float* __restrict__ vals,
                            const int* __restrict__ i_idx,
                            const int* __restrict__ j_idx,
                            int nnz,
                            int* __restrict__ seg_start,
                            int* __restrict__ seg_end,
                            int2* __restrict__ packed) {
    int n = blockIdx.x * blockDim.x + threadIdx.x;
    if (n >= nnz) return;
    int k = k_idx[n];
    if (n == 0 || k_idx[n - 1] != k) seg_start[k] = n;
    if (n == nnz - 1 || k_idx[n + 1] != k) seg_end[k] = n + 1;
    packed[n] = make_int2(i_idx[n] | (j_idx[n] << 16), __float_as_int(vals[n]));
}

__global__ __launch_bounds__(BLK) void tp_kernel(
        const float* __restrict__ x1,
        const float* __restrict__ x2,
        const int2* __restrict__ packed,
        const int* __restrict__ seg_start,
        const int* __restrict__ seg_end,
        float* __restrict__ out,
        int dim_out) {
    __shared__ __align__(16) float x1s[DIM_IN * STRIDE];
    __shared__ __align__(16) float x2s[DIM_IN * STRIDE];

    const int z0 = blockIdx.y * ZPT;
    const int k  = blockIdx.x * BLK + threadIdx.x;

    // issue bounds loads early (independent of staging)
    int s = 0, e = 0;
    if (k < dim_out) {
        s = seg_start[k];
        e = seg_end[k];
    }

    // stage transposed: x1s[i*STRIDE + t] = x1[(z0+t)*DIM_IN + i]
    for (int idx = threadIdx.x; idx < ZPT * (DIM_IN / 4); idx += BLK) {
        const int t  = idx / (DIM_IN / 4);
        const int i4 = idx % (DIM_IN / 4);
        const float4 a = *(const float4*)(x1 + (size_t)(z0 + t) * DIM_IN + i4 * 4);
        const float4 b = *(const float4*)(x2 + (size_t)(z0 + t) * DIM_IN + i4 * 4);
        const int base = i4 * 4 * STRIDE + t;
        x1s[base             ] = a.x;
        x1s[base +     STRIDE] = a.y;
        x1s[base + 2 * STRIDE] = a.z;
        x1s[base + 3 * STRIDE] = a.w;
        x2s[base             ] = b.x;
        x2s[base +     STRIDE] = b.y;
        x2s[base + 2 * STRIDE] = b.z;
        x2s[base + 3 * STRIDE] = b.w;
    }
    __syncthreads();

    if (k >= dim_out) return;

    float acc[ZPT];
#pragma unroll
    for (int t = 0; t < ZPT; ++t) acc[t] = 0.0f;

    // software-pipelined entry loop: next packed load in flight during compute
    int n = s;
    if (n < e) {
        int2 ev = packed[n];
        for (;;) {
            const bool more = (n + 1 < e);
            int2 evn;
            if (more) evn = packed[n + 1];

            const float c = __int_as_float(ev.y);
            const int i = ev.x & 0xffff;
            const int j = ev.x >> 16;
            const float4* p1 = (const float4*)(x1s + i * STRIDE);
            const float4* p2 = (const float4*)(x2s + j * STRIDE);
#pragma unroll
            for (int q = 0; q < ZPT / 4; ++q) {
                const float4 a = p1[q];
                const float4 b = p2[q];
                acc[4 * q + 0] += c * a.x * b.x;
                acc[4 * q + 1] += c * a.y * b.y;
                acc[4 * q + 2] += c * a.z * b.z;
                acc[4 * q + 3] += c * a.w * b.w;
            }

            ++n;
            if (!more) break;
            ev = evn;
        }
    }

    // coalesced stores: consecutive lanes -> consecutive k
#pragma unroll
    for (int t = 0; t < ZPT; ++t) {
        out[(size_t)(z0 + t) * dim_out + k] = acc[t];
    }
}

extern "C" void kernel_launch(void* const* d_in, const int* in_sizes, int n_in,
                              void* d_out, int out_size, void* d_ws, size_t ws_size,
                              hipStream_t stream) {
    const float* x1   = (const float*)d_in[0];
    const float* x2   = (const float*)d_in[1];
    const float* vals = (const float*)d_in[2];
    const int*   kidx = (const int*)d_in[3];
    const int*   iidx = (const int*)d_in[4];
    const int*   jidx = (const int*)d_in[5];
    float* out = (float*)d_out;

    const int n_batch = 1024;                  // N_BATCH in the reference
    const int dim_out = out_size / n_batch;    // 20736
    const int nnz     = in_sizes[2];

    // workspace: seg_start[dim_out], seg_end[dim_out], packed int2[nnz]
    int*  seg_start = (int*)d_ws;
    int*  seg_end   = seg_start + dim_out;
    int2* packed    = (int2*)(seg_end + dim_out);   // 8*dim_out bytes in, 8B-aligned

    {
        int grid = (nnz + 255) / 256;
        prep_kernel<<<grid, 256, 0, stream>>>(kidx, vals, iidx, jidx, nnz,
                                              seg_start, seg_end, packed);
    }

    {
        dim3 grid((dim_out + BLK - 1) / BLK, 1024 / ZPT);
        tp_kernel<<<grid, BLK, 0, stream>>>(x1, x2, packed,
                                            seg_start, seg_end, out, dim_out);
    }
}